// Round 8
// baseline (165.098 us; speedup 1.0000x reference)
//
#include <hip/hip_runtime.h>
#include <math.h>

#define L_LEN 16384
#define M_LEN 8192
#define KT_LEN 4096
#define BB 32
#define NTPL 50
#define SPEC_STRIDE 8224   // complex slots per signal (>= 8193)
#define NSIG 166           // 64 x-signals + 2 w-signals + 100 templates
#define NT 512
#define PI_F 3.14159265358979323846f
// cos/sin(pi/16): stage-3 twiddle base (es=512)
#define C16 0.98078528040323044f
#define S16 0.19509032201612827f

typedef float cf2 __attribute__((ext_vector_type(2)));

__device__ __forceinline__ cf2 cmul(cf2 a, cf2 b) {
    cf2 byx = __builtin_shufflevector(b, b, 1, 0);   // (by,bx)
    return (cf2){a.x, a.x} * b + (cf2){-a.y, a.y} * byx;
}
__device__ __forceinline__ cf2 cmulc(cf2 a, cf2 b) { // a * conj(b)
    return a * (cf2){b.x, b.x} + (cf2){a.y, -a.x} * (cf2){b.y, b.y};
}
template<int SIGN>
__device__ __forceinline__ cf2 rot90(cf2 z) {
    return (SIGN < 0) ? (cf2){z.y, -z.x} : (cf2){-z.y, z.x};
}
template<int SIGN>
__device__ __forceinline__ cf2 ldT(const cf2* __restrict__ T, int idx) {
    cf2 t = T[idx];
    if (SIGN > 0) t.y = -t.y;
    return t;
}

// LDS bank swizzle (R6-proven; R7's pad layout tripled conflicts — reverted).
// Even XOR keeps float4 pair adjacency. Involution -> bijective.
__device__ __forceinline__ int swz(int i) { return i ^ (((i >> 5) & 15) << 1); }

// Position of frequency f after radix 16,16,16,2 DIF stages (digit reversal).
__device__ __forceinline__ int pos(int f) {
    return ((f & 15) << 9) | (((f >> 4) & 15) << 5) |
           (((f >> 8) & 15) << 1) | ((f >> 12) & 1);
}

// 16-point DFT in registers, natural order. Inner twiddles are constants.
template<int SIGN>
__device__ __forceinline__ void dft16(cf2 x[16]) {
    const float S = (SIGN < 0) ? -1.f : 1.f;
    const cf2 w1 = {0.9238795325112867f, S * 0.3826834323650898f};
    const cf2 w2 = {0.7071067811865476f, S * 0.7071067811865476f};
    const cf2 w3 = {0.3826834323650898f, S * 0.9238795325112867f};
    cf2 v[16];
    #pragma unroll
    for (int n1 = 0; n1 < 4; ++n1) {
        cf2 a0 = x[n1], a1 = x[n1+4], a2 = x[n1+8], a3 = x[n1+12];
        cf2 t0 = a0 + a2, t2 = a0 - a2;
        cf2 t1 = a1 + a3, t3 = rot90<SIGN>(a1 - a3);
        cf2 u0 = t0 + t1, u1 = t2 + t3;
        cf2 u2 = t0 - t1, u3 = t2 - t3;
        if (n1 == 1) { u1 = cmul(u1, w1); u2 = cmul(u2, w2); u3 = cmul(u3, w3); }
        else if (n1 == 2) { u1 = cmul(u1, w2); u2 = rot90<SIGN>(u2);
                            u3 = rot90<SIGN>(cmul(u3, w2)); }
        else if (n1 == 3) { u1 = cmul(u1, w3); u2 = rot90<SIGN>(cmul(u2, w2));
                            u3 = -cmul(u3, w1); }
        v[0*4+n1] = u0; v[1*4+n1] = u1; v[2*4+n1] = u2; v[3*4+n1] = u3;
    }
    #pragma unroll
    for (int r = 0; r < 4; ++r) {
        cf2 a0 = v[r*4+0], a1 = v[r*4+1], a2 = v[r*4+2], a3 = v[r*4+3];
        cf2 t0 = a0 + a2, t2 = a0 - a2;
        cf2 t1 = a1 + a3, t3 = rot90<SIGN>(a1 - a3);
        x[r]    = t0 + t1; x[r+4]  = t2 + t3;
        x[r+8]  = t0 - t1; x[r+12] = t2 - t3;
    }
}

// Radix-16 butterfly at 16 precomputed LDS indices; outer twiddles from a
// single w1 via power chain (R5: scattered table loads were the stall).
template<int SIGN>
__device__ __forceinline__ void butterfly16(cf2* A, const int idx[16], cf2 w1) {
    cf2 x[16];
    #pragma unroll
    for (int n = 0; n < 16; ++n) x[n] = A[idx[n]];
    dft16<SIGN>(x);
    A[idx[0]] = x[0];
    A[idx[1]] = cmul(x[1], w1);
    const cf2 w2 = cmul(w1, w1);
    A[idx[2]] = cmul(x[2], w2);
    const cf2 w3 = cmul(w1, w2);
    A[idx[3]] = cmul(x[3], w3);
    const cf2 w4 = cmul(w2, w2);
    A[idx[4]] = cmul(x[4], w4);
    A[idx[5]] = cmul(x[5], cmul(w1, w4));
    A[idx[6]] = cmul(x[6], cmul(w2, w4));
    A[idx[7]] = cmul(x[7], cmul(w3, w4));
    const cf2 w8 = cmul(w4, w4);
    A[idx[8]]  = cmul(x[8],  w8);
    A[idx[9]]  = cmul(x[9],  cmul(w1, w8));
    A[idx[10]] = cmul(x[10], cmul(w2, w8));
    A[idx[11]] = cmul(x[11], cmul(w3, w8));
    const cf2 w12 = cmul(w4, w8);
    A[idx[12]] = cmul(x[12], w12);
    A[idx[13]] = cmul(x[13], cmul(w1, w12));
    A[idx[14]] = cmul(x[14], cmul(w2, w12));
    A[idx[15]] = cmul(x[15], cmul(w3, w12));
}

// Per-stage swizzled index sets, algebraically reduced (verified):
// stage1: swz(tid+512n)        = swz(tid) + 512n
// stage2: swz(blk*512+j+32n)   = blk*512 + 32n + (j^2n)        (j in [0,32))
// stage3: swz(blk*32+j+2n)     = blk*32 + j + ((2n)^((blk&15)<<1))

// ---------------------------------------------------------------------------
// Kernel 1: forward real FFT (length 16384) via 8192-pt complex FFT.
// Blocks [NSIG, NSIG+32) instead build the twiddle table T (used by later
// kernels only — fwd itself uses inline __sincosf, so no dependency).
// ---------------------------------------------------------------------------
__global__ __launch_bounds__(NT, 4)
void fwd_fft_kernel(const float* __restrict__ xi, const float* __restrict__ w,
                    const float* __restrict__ tmpl, cf2* __restrict__ Tw,
                    cf2* __restrict__ spec) {
    __shared__ __attribute__((aligned(16))) cf2 A[M_LEN];   // 64 KB
    const int sig = blockIdx.x;
    const int tid = threadIdx.x;

    if (sig >= NSIG) {   // twiddle writer: T[k] = e^{-2 pi i k / 16384}
        const int k = (sig - NSIG) * NT + tid;
        const double a = -M_PI * (double)k / 8192.0;
        Tw[k] = (cf2){(float)cos(a), (float)sin(a)};
        return;
    }

    const float* src;
    int nre;
    if (sig < 64)      { src = xi   + sig * L_LEN;         nre = L_LEN; }
    else if (sig < 66) { src = w    + (sig - 64) * L_LEN;  nre = L_LEN; }
    else               { src = tmpl + (sig - 66) * KT_LEN; nre = KT_LEN; }
    const int nc = nre >> 1;
    const float4* s4 = (const float4*)src;
    const int g0 = tid ^ ((tid >> 4) & 15);   // = swz(2*tid+1024m)>>1 − 512m
    #pragma unroll
    for (int m = 0; m < 8; ++m) {
        const int u = 2*tid + 1024*m;
        float4 vv = (u < nc) ? s4[tid + 512*m] : make_float4(0.f, 0.f, 0.f, 0.f);
        ((float4*)A)[g0 + 512*m] = vv;
    }
    __syncthreads();

    {   // stage 1: stride 512, es = 2*tid
        int idx[16]; const int b0 = swz(tid);
        #pragma unroll
        for (int n = 0; n < 16; ++n) idx[n] = b0 + 512*n;
        float sn, cs; __sincosf(-PI_F * (float)(2*tid) / 8192.f, &sn, &cs);
        butterfly16<-1>(A, idx, (cf2){cs, sn});
    }
    __syncthreads();
    {   // stage 2: stride 32, es = 32*j
        const int blk = tid >> 5, j = tid & 31, jb = blk*512;
        int idx[16];
        #pragma unroll
        for (int n = 0; n < 16; ++n) idx[n] = jb + 32*n + (j ^ (2*n));
        float sn, cs; __sincosf(-PI_F * (float)(32*j) / 8192.f, &sn, &cs);
        butterfly16<-1>(A, idx, (cf2){cs, sn});
    }
    __syncthreads();
    {   // stage 3: stride 2, es = 512*j
        const int blk = tid >> 1, j = tid & 1;
        const int xv = (blk & 15) << 1, b3 = blk*32 + j;
        int idx[16];
        #pragma unroll
        for (int n = 0; n < 16; ++n) idx[n] = b3 + ((2*n) ^ xv);
        cf2 w1 = j ? (cf2){C16, -S16} : (cf2){1.f, 0.f};
        butterfly16<-1>(A, idx, w1);
    }
    __syncthreads();
    // Final radix-2 (stride 1, no twiddle), b128 in-place.
    #pragma unroll
    for (int m = 0; m < 8; ++m) {
        float4 pq = ((float4*)A)[g0 + 512*m];
        ((float4*)A)[g0 + 512*m] = make_float4(pq.x + pq.z, pq.y + pq.w,
                                               pq.x - pq.z, pq.y - pq.w);
    }
    __syncthreads();

    // Untangle packed result to real-signal spectrum X[f], f = 0..M.
    cf2* out = spec + (size_t)sig * SPEC_STRIDE;
    #pragma unroll
    for (int m = 0; m < 16; ++m) {
        const int f = tid + 512*m;
        const int fb = (M_LEN - f) & (M_LEN - 1);
        cf2 Za = A[swz(pos(f))];
        cf2 Zb = A[swz(pos(fb))];
        cf2 E = (cf2){0.5f*(Za.x + Zb.x), 0.5f*(Za.y - Zb.y)};
        cf2 D = (cf2){Za.x - Zb.x, Za.y + Zb.y};
        cf2 O = (cf2){0.5f*D.y, -0.5f*D.x};
        float sn, cs;
        __sincosf(-PI_F * (float)f / 8192.f, &sn, &cs);
        cf2 TO = (cf2){cs*O.x - sn*O.y, cs*O.y + sn*O.x};
        out[f] = E + TO;
    }
    if (tid == 0) {   // f = 8192
        cf2 Za = A[swz(0)];
        out[M_LEN] = (cf2){Za.x - Za.y, 0.f};
    }
}

// ---------------------------------------------------------------------------
// Kernel 1.5: per (b,c) premultiply: D[f] = X[f]*conj(W[f])*phase(f), with
// phase(f) = conj(T[2f mod 16K]) * (-i)^f  (coalesced T loads).
// ---------------------------------------------------------------------------
__global__ __launch_bounds__(512)
void premul_kernel(const cf2* __restrict__ T, cf2* __restrict__ spec) {
    const int bc = blockIdx.x;
    const int tid = threadIdx.x;
    const int c = bc & 1;
    cf2* Xs = spec + (size_t)bc * SPEC_STRIDE;
    const cf2* Ws = spec + (size_t)(64 + c) * SPEC_STRIDE;
    const int r = tid & 3;   // f == tid (mod 4) for every iteration
    for (int f = tid; f <= M_LEN; f += 512) {
        cf2 t = cmulc(Xs[f], Ws[f]);
        cf2 p = T[(2*f) & (L_LEN - 1)];
        cf2 s = cmulc(t, p);
        cf2 o;
        if (r == 0)      o = s;
        else if (r == 1) o = (cf2){s.y, -s.x};    // * -i
        else if (r == 2) o = -s;
        else             o = (cf2){-s.y, s.x};    // * +i
        Xs[f] = o;
    }
}

// ---------------------------------------------------------------------------
// Kernel 2: per (b,n,c): S[f] = D[f]*conj(H[f]); Hermitian pack fused into
// the product pass; stages 1-2 in LDS (R6 XOR-swizzle layout); stage 3 +
// final radix-2 + max in registers via shfl_xor(1) (DPP quad-perm, no LDS).
// ---------------------------------------------------------------------------
__global__ __launch_bounds__(NT, 4)
void inv_fft_kernel(const cf2* __restrict__ spec, const cf2* __restrict__ T,
                    const float* __restrict__ hh, float* __restrict__ zarr) {
    __shared__ __attribute__((aligned(16))) cf2 A[M_LEN];   // 64 KB
    const int idx0 = blockIdx.x;
    const int c = idx0 & 1;
    const int n = (idx0 >> 1) % NTPL;
    const int b = idx0 / (2 * NTPL);
    const int tid = threadIdx.x;

    const cf2* Ds = spec + (size_t)(b*2 + c)      * SPEC_STRIDE;
    const cf2* Hs = spec + (size_t)(66 + n*2 + c) * SPEC_STRIDE;
    const float4* D4 = (const float4*)Ds;
    const float4* H4 = (const float4*)Hs;
    const float4* T4 = (const float4*)T;
    const int g0 = tid ^ ((tid >> 4) & 15);

    // Fused product + Hermitian pack: thread t handles f = 2t+1024m+{0,1}
    // (f in [0,4096)) and partners 8192-f. Writes all of Z'[0..8191].
    #pragma unroll
    for (int m = 0; m < 4; ++m) {
        const int u = 2*tid + 1024*m;
        float4 df = D4[tid + 512*m], hf = H4[tid + 512*m];
        cf2 Sa0 = cmulc((cf2){df.x, df.y}, (cf2){hf.x, hf.y});
        cf2 Sa1 = cmulc((cf2){df.z, df.w}, (cf2){hf.z, hf.w});
        cf2 Sb0 = cmulc(Ds[M_LEN - u],     Hs[M_LEN - u]);
        cf2 Sb1 = cmulc(Ds[M_LEN - 1 - u], Hs[M_LEN - 1 - u]);
        float4 tw = T4[tid + 512*m];          // T[u], T[u+1]
        // f = u
        float cs0 = tw.x, sn0 = -tw.y;
        float Ex0 = 0.5f*(Sa0.x + Sb0.x), Ey0 = 0.5f*(Sa0.y - Sb0.y);
        float Dx0 = Sa0.x - Sb0.x,        Dy0 = Sa0.y + Sb0.y;
        float Ox0 = 0.5f*(cs0*Dx0 - sn0*Dy0), Oy0 = 0.5f*(cs0*Dy0 + sn0*Dx0);
        // f = u+1
        float cs1 = tw.z, sn1 = -tw.w;
        float Ex1 = 0.5f*(Sa1.x + Sb1.x), Ey1 = 0.5f*(Sa1.y - Sb1.y);
        float Dx1 = Sa1.x - Sb1.x,        Dy1 = Sa1.y + Sb1.y;
        float Ox1 = 0.5f*(cs1*Dx1 - sn1*Dy1), Oy1 = 0.5f*(cs1*Dy1 + sn1*Dx1);
        ((float4*)A)[g0 + 512*m] = make_float4(Ex0 - Oy0, Ey0 + Ox0,
                                               Ex1 - Oy1, Ey1 + Ox1);
        if (u > 0) A[swz(M_LEN - u)] = (cf2){Ex0 + Oy0, Ox0 - Ey0};
        A[swz(M_LEN - 1 - u)] = (cf2){Ex1 + Oy1, Ox1 - Ey1};
    }
    if (tid == 0) {   // f = 4096 (self-paired)
        cf2 S = cmulc(Ds[4096], Hs[4096]);
        A[swz(4096)] = (cf2){S.x, -S.y};
    }
    __syncthreads();

    {   // stage 1: stride 512, es = 2*tid
        int idx[16]; const int b0 = swz(tid);
        #pragma unroll
        for (int nn = 0; nn < 16; ++nn) idx[nn] = b0 + 512*nn;
        butterfly16<+1>(A, idx, ldT<+1>(T, 2*tid));
    }
    __syncthreads();
    {   // stage 2: stride 32, es = 32*j
        const int blk = tid >> 5, j = tid & 31, jb = blk*512;
        int idx[16];
        #pragma unroll
        for (int nn = 0; nn < 16; ++nn) idx[nn] = jb + 32*nn + (j ^ (2*nn));
        butterfly16<+1>(A, idx, ldT<+1>(T, 32*j));
    }
    __syncthreads();

    // Stage 3 in registers + final radix-2 via shfl_xor(1) + max (no LDS).
    float mx = -INFINITY;
    {
        const int blk = tid >> 1, j = tid & 1;
        const int xv = (blk & 15) << 1, b3 = blk*32 + j;
        cf2 x[16];
        #pragma unroll
        for (int nn = 0; nn < 16; ++nn) x[nn] = A[b3 + ((2*nn) ^ xv)];
        dft16<+1>(x);
        cf2 w1 = j ? (cf2){C16, S16} : (cf2){1.f, 0.f};
        auto acc = [&](cf2 z) {
            float qx = __shfl_xor(z.x, 1), qy = __shfl_xor(z.y, 1);
            float sx = z.x + qx, sy = z.y + qy;
            float dx = j ? qx - z.x : z.x - qx;   // both lanes = z(j0)-z(j1)
            float dy = j ? qy - z.y : z.y - qy;
            mx = fmaxf(mx, fmaxf(fmaxf(sx, sy), fmaxf(dx, dy)));
        };
        acc(x[0]);
        acc(cmul(x[1], w1));
        const cf2 w2 = cmul(w1, w1);
        acc(cmul(x[2], w2));
        const cf2 w3 = cmul(w1, w2);
        acc(cmul(x[3], w3));
        const cf2 w4 = cmul(w2, w2);
        acc(cmul(x[4], w4));
        acc(cmul(x[5], cmul(w1, w4)));
        acc(cmul(x[6], cmul(w2, w4)));
        acc(cmul(x[7], cmul(w3, w4)));
        const cf2 w8 = cmul(w4, w4);
        acc(cmul(x[8],  w8));
        acc(cmul(x[9],  cmul(w1, w8)));
        acc(cmul(x[10], cmul(w2, w8)));
        acc(cmul(x[11], cmul(w3, w8)));
        const cf2 w12 = cmul(w4, w8);
        acc(cmul(x[12], w12));
        acc(cmul(x[13], cmul(w1, w12)));
        acc(cmul(x[14], cmul(w2, w12)));
        acc(cmul(x[15], cmul(w3, w12)));
    }
    for (int off = 32; off > 0; off >>= 1)
        mx = fmaxf(mx, __shfl_xor(mx, off));
    __syncthreads();   // all stage-3 reads of A done before reusing as scratch
    const int lane = tid & 63, wv = tid >> 6;   // 8 waves
    float* redf = (float*)A;
    if (lane == 0) redf[wv] = mx;
    __syncthreads();
    if (tid == 0) {
        float mm = redf[0];
        for (int i = 1; i < NT/64; ++i) mm = fmaxf(mm, redf[i]);
        zarr[(b*2 + c)*NTPL + n] = mm / ((float)M_LEN * hh[n*2 + c]);
    }
}

// ---------------------------------------------------------------------------
// Kernel 3: tiny CNN/MLP head. One block per batch element.
// ---------------------------------------------------------------------------
__global__ __launch_bounds__(256)
void head_kernel(const float* __restrict__ zarr,
                 const float* __restrict__ W1, const float* __restrict__ b1,
                 const float* __restrict__ W2, const float* __restrict__ b2,
                 const float* __restrict__ W3, const float* __restrict__ b3,
                 const float* __restrict__ W4, const float* __restrict__ b4,
                 float* __restrict__ out) {
    __shared__ float zl[2][NTPL];
    __shared__ float s1[16][48];
    __shared__ float p1[16][16];
    __shared__ float s2[32][14];
    __shared__ float hflat[128];
    __shared__ float h1[32];
    const int b = blockIdx.x, tid = threadIdx.x;

    for (int i = tid; i < 2*NTPL; i += 256) zl[i/NTPL][i%NTPL] = zarr[b*2*NTPL + i];
    __syncthreads();
    for (int i = tid; i < 16*48; i += 256) {
        const int o = i / 48, t = i % 48;
        float acc = b1[o];
        #pragma unroll
        for (int cc = 0; cc < 2; ++cc)
            #pragma unroll
            for (int k = 0; k < 3; ++k)
                acc += zl[cc][t+k] * W1[o*6 + cc*3 + k];
        s1[o][t] = 1.f / (1.f + __expf(-acc));
    }
    __syncthreads();
    for (int i = tid; i < 16*16; i += 256) {
        const int o = i / 16, u = i % 16;
        p1[o][u] = fmaxf(fmaxf(s1[o][3*u], s1[o][3*u+1]), s1[o][3*u+2]);
    }
    __syncthreads();
    for (int i = tid; i < 32*14; i += 256) {
        const int o = i / 14, t = i % 14;
        float acc = b2[o];
        for (int cc = 0; cc < 16; ++cc)
            #pragma unroll
            for (int k = 0; k < 3; ++k)
                acc += p1[cc][t+k] * W2[o*48 + cc*3 + k];
        s2[o][t] = 1.f / (1.f + __expf(-acc));
    }
    __syncthreads();
    for (int i = tid; i < 128; i += 256) {
        const int o = i / 4, u = i % 4;
        hflat[i] = fmaxf(fmaxf(s2[o][3*u], s2[o][3*u+1]), s2[o][3*u+2]);
    }
    __syncthreads();
    if (tid < 32) {
        float acc = b3[tid];
        for (int j = 0; j < 128; ++j) acc += hflat[j] * W3[tid*128 + j];
        h1[tid] = fmaxf(acc, 0.f);
    }
    __syncthreads();
    if (tid < 2) {
        float acc = b4[tid];
        for (int j = 0; j < 32; ++j) acc += h1[j] * W4[tid*32 + j];
        out[b*2 + tid] = acc;
    }
}

extern "C" void kernel_launch(void* const* d_in, const int* in_sizes, int n_in,
                              void* d_out, int out_size, void* d_ws, size_t ws_size,
                              hipStream_t stream) {
    const float* xi   = (const float*)d_in[0];
    const float* Sw   = (const float*)d_in[1];
    const float* tmpl = (const float*)d_in[2];
    const float* hh   = (const float*)d_in[3];
    const float* W1   = (const float*)d_in[4];
    const float* b1   = (const float*)d_in[5];
    const float* W2   = (const float*)d_in[6];
    const float* b2   = (const float*)d_in[7];
    const float* W3   = (const float*)d_in[8];
    const float* b3   = (const float*)d_in[9];
    const float* W4   = (const float*)d_in[10];
    const float* b4   = (const float*)d_in[11];
    float* out = (float*)d_out;

    cf2* T16  = (cf2*)d_ws;                         // 16384 cf2 = 128 KB
    cf2* spec = T16 + 16384;                        // NSIG * SPEC_STRIDE cf2
    float* zarr = (float*)(spec + (size_t)NSIG * SPEC_STRIDE);

    // fwd grid: NSIG FFT blocks + 32 twiddle-table writer blocks.
    fwd_fft_kernel<<<dim3(NSIG + 32), dim3(NT), 0, stream>>>(xi, Sw, tmpl, T16, spec);
    premul_kernel<<<dim3(64), dim3(512), 0, stream>>>(T16, spec);
    inv_fft_kernel<<<dim3(BB * NTPL * 2), dim3(NT), 0, stream>>>(spec, T16, hh, zarr);
    head_kernel<<<dim3(BB), dim3(256), 0, stream>>>(zarr, W1, b1, W2, b2, W3, b3, W4, b4, out);
}

// Round 9
// 157.705 us; speedup vs baseline: 1.0469x; 1.0469x over previous
//
#include <hip/hip_runtime.h>
#include <math.h>

#define L_LEN 16384
#define M_LEN 8192
#define KT_LEN 4096
#define BB 32
#define NTPL 50
#define SPEC_STRIDE 8224   // complex slots per signal (>= 8193)
#define NSIG 166           // 64 x-signals + 2 w-signals + 100 templates
#define NT 512
#define PI_F 3.14159265358979323846f
// cos/sin(pi/16): stage-3 twiddle base (es=512)
#define C16 0.98078528040323044f
#define S16 0.19509032201612827f

typedef float cf2 __attribute__((ext_vector_type(2)));

// Lessons encoded in this structure:
//  R5: scattered per-lane twiddle table loads stall VMEM -> power chain from 1 load.
//  R6: XOR swizzle + cf2 packed math + algebraic per-stage indices = best layout.
//  R7: +1-per-32 pad layout TRIPLES bank conflicts vs XOR swizzle. Don't.
//  R8: __shfl_xor compiles to ds_bpermute (LDS pipe!) - shfl-based stage-3
//      fusion is slower than plain LDS stage 3 + b128 final pass. Don't.

__device__ __forceinline__ cf2 cmul(cf2 a, cf2 b) {
    cf2 byx = __builtin_shufflevector(b, b, 1, 0);   // (by,bx)
    return (cf2){a.x, a.x} * b + (cf2){-a.y, a.y} * byx;
}
__device__ __forceinline__ cf2 cmulc(cf2 a, cf2 b) { // a * conj(b)
    return a * (cf2){b.x, b.x} + (cf2){a.y, -a.x} * (cf2){b.y, b.y};
}
template<int SIGN>
__device__ __forceinline__ cf2 rot90(cf2 z) {
    return (SIGN < 0) ? (cf2){z.y, -z.x} : (cf2){-z.y, z.x};
}
template<int SIGN>
__device__ __forceinline__ cf2 ldT(const cf2* __restrict__ T, int idx) {
    cf2 t = T[idx];
    if (SIGN > 0) t.y = -t.y;
    return t;
}

// LDS bank swizzle. Even XOR keeps float4 pair adjacency; involution.
__device__ __forceinline__ int swz(int i) { return i ^ (((i >> 5) & 15) << 1); }

// Position of frequency f after radix 16,16,16,2 DIF stages (digit reversal).
__device__ __forceinline__ int pos(int f) {
    return ((f & 15) << 9) | (((f >> 4) & 15) << 5) |
           (((f >> 8) & 15) << 1) | ((f >> 12) & 1);
}

// 16-point DFT in registers, natural order. Inner twiddles are constants.
template<int SIGN>
__device__ __forceinline__ void dft16(cf2 x[16]) {
    const float S = (SIGN < 0) ? -1.f : 1.f;
    const cf2 w1 = {0.9238795325112867f, S * 0.3826834323650898f};
    const cf2 w2 = {0.7071067811865476f, S * 0.7071067811865476f};
    const cf2 w3 = {0.3826834323650898f, S * 0.9238795325112867f};
    cf2 v[16];
    #pragma unroll
    for (int n1 = 0; n1 < 4; ++n1) {
        cf2 a0 = x[n1], a1 = x[n1+4], a2 = x[n1+8], a3 = x[n1+12];
        cf2 t0 = a0 + a2, t2 = a0 - a2;
        cf2 t1 = a1 + a3, t3 = rot90<SIGN>(a1 - a3);
        cf2 u0 = t0 + t1, u1 = t2 + t3;
        cf2 u2 = t0 - t1, u3 = t2 - t3;
        if (n1 == 1) { u1 = cmul(u1, w1); u2 = cmul(u2, w2); u3 = cmul(u3, w3); }
        else if (n1 == 2) { u1 = cmul(u1, w2); u2 = rot90<SIGN>(u2);
                            u3 = rot90<SIGN>(cmul(u3, w2)); }
        else if (n1 == 3) { u1 = cmul(u1, w3); u2 = rot90<SIGN>(cmul(u2, w2));
                            u3 = -cmul(u3, w1); }
        v[0*4+n1] = u0; v[1*4+n1] = u1; v[2*4+n1] = u2; v[3*4+n1] = u3;
    }
    #pragma unroll
    for (int r = 0; r < 4; ++r) {
        cf2 a0 = v[r*4+0], a1 = v[r*4+1], a2 = v[r*4+2], a3 = v[r*4+3];
        cf2 t0 = a0 + a2, t2 = a0 - a2;
        cf2 t1 = a1 + a3, t3 = rot90<SIGN>(a1 - a3);
        x[r]    = t0 + t1; x[r+4]  = t2 + t3;
        x[r+8]  = t0 - t1; x[r+12] = t2 - t3;
    }
}

// Radix-16 butterfly at 16 precomputed LDS indices; outer twiddles from a
// single w1 via power chain.
template<int SIGN>
__device__ __forceinline__ void butterfly16(cf2* A, const int idx[16], cf2 w1) {
    cf2 x[16];
    #pragma unroll
    for (int n = 0; n < 16; ++n) x[n] = A[idx[n]];
    dft16<SIGN>(x);
    A[idx[0]] = x[0];
    A[idx[1]] = cmul(x[1], w1);
    const cf2 w2 = cmul(w1, w1);
    A[idx[2]] = cmul(x[2], w2);
    const cf2 w3 = cmul(w1, w2);
    A[idx[3]] = cmul(x[3], w3);
    const cf2 w4 = cmul(w2, w2);
    A[idx[4]] = cmul(x[4], w4);
    A[idx[5]] = cmul(x[5], cmul(w1, w4));
    A[idx[6]] = cmul(x[6], cmul(w2, w4));
    A[idx[7]] = cmul(x[7], cmul(w3, w4));
    const cf2 w8 = cmul(w4, w4);
    A[idx[8]]  = cmul(x[8],  w8);
    A[idx[9]]  = cmul(x[9],  cmul(w1, w8));
    A[idx[10]] = cmul(x[10], cmul(w2, w8));
    A[idx[11]] = cmul(x[11], cmul(w3, w8));
    const cf2 w12 = cmul(w4, w8);
    A[idx[12]] = cmul(x[12], w12);
    A[idx[13]] = cmul(x[13], cmul(w1, w12));
    A[idx[14]] = cmul(x[14], cmul(w2, w12));
    A[idx[15]] = cmul(x[15], cmul(w3, w12));
}

// Per-stage swizzled index sets, algebraically reduced (verified):
// stage1: swz(tid+512n)        = swz(tid) + 512n
// stage2: swz(blk*512+j+32n)   = blk*512 + 32n + (j^2n)        (j in [0,32))
// stage3: swz(blk*32+j+2n)     = blk*32 + j + ((2n)^((blk&15)<<1))

// ---------------------------------------------------------------------------
// Kernel 1: forward real FFT (length 16384) via 8192-pt complex FFT.
// Blocks [NSIG, NSIG+32) build the twiddle table T (used by inv only).
// W blocks (sig 64/65) write V(f) = conj(W(f)) * e^{-i pi k/8192},
// k = 4094*f mod 16384 — this absorbs the old premul kernel entirely.
// ---------------------------------------------------------------------------
__global__ __launch_bounds__(NT, 4)
void fwd_fft_kernel(const float* __restrict__ xi, const float* __restrict__ w,
                    const float* __restrict__ tmpl, cf2* __restrict__ Tw,
                    cf2* __restrict__ spec) {
    __shared__ __attribute__((aligned(16))) cf2 A[M_LEN];   // 64 KB
    const int sig = blockIdx.x;
    const int tid = threadIdx.x;

    if (sig >= NSIG) {   // twiddle writer: T[k] = e^{-2 pi i k / 16384}
        const int k = (sig - NSIG) * NT + tid;
        const double a = -M_PI * (double)k / 8192.0;
        Tw[k] = (cf2){(float)cos(a), (float)sin(a)};
        return;
    }

    const float* src;
    int nre;
    if (sig < 64)      { src = xi   + sig * L_LEN;         nre = L_LEN; }
    else if (sig < 66) { src = w    + (sig - 64) * L_LEN;  nre = L_LEN; }
    else               { src = tmpl + (sig - 66) * KT_LEN; nre = KT_LEN; }
    const bool isW = (sig >= 64 && sig < 66);
    const int nc = nre >> 1;
    const float4* s4 = (const float4*)src;
    const int g0 = tid ^ ((tid >> 4) & 15);   // = swz(2*tid+1024m)>>1 − 512m
    #pragma unroll
    for (int m = 0; m < 8; ++m) {
        const int u = 2*tid + 1024*m;
        float4 vv = (u < nc) ? s4[tid + 512*m] : make_float4(0.f, 0.f, 0.f, 0.f);
        ((float4*)A)[g0 + 512*m] = vv;
    }
    __syncthreads();

    {   // stage 1: stride 512, es = 2*tid
        int idx[16]; const int b0 = swz(tid);
        #pragma unroll
        for (int n = 0; n < 16; ++n) idx[n] = b0 + 512*n;
        float sn, cs; __sincosf(-PI_F * (float)(2*tid) / 8192.f, &sn, &cs);
        butterfly16<-1>(A, idx, (cf2){cs, sn});
    }
    __syncthreads();
    {   // stage 2: stride 32, es = 32*j
        const int blk = tid >> 5, j = tid & 31, jb = blk*512;
        int idx[16];
        #pragma unroll
        for (int n = 0; n < 16; ++n) idx[n] = jb + 32*n + (j ^ (2*n));
        float sn, cs; __sincosf(-PI_F * (float)(32*j) / 8192.f, &sn, &cs);
        butterfly16<-1>(A, idx, (cf2){cs, sn});
    }
    __syncthreads();
    {   // stage 3: stride 2, es = 512*j
        const int blk = tid >> 1, j = tid & 1;
        const int xv = (blk & 15) << 1, b3 = blk*32 + j;
        int idx[16];
        #pragma unroll
        for (int n = 0; n < 16; ++n) idx[n] = b3 + ((2*n) ^ xv);
        cf2 w1 = j ? (cf2){C16, -S16} : (cf2){1.f, 0.f};
        butterfly16<-1>(A, idx, w1);
    }
    __syncthreads();
    // Final radix-2 (stride 1, no twiddle), b128 in-place.
    #pragma unroll
    for (int m = 0; m < 8; ++m) {
        float4 pq = ((float4*)A)[g0 + 512*m];
        ((float4*)A)[g0 + 512*m] = make_float4(pq.x + pq.z, pq.y + pq.w,
                                               pq.x - pq.z, pq.y - pq.w);
    }
    __syncthreads();

    // Untangle packed result to real-signal spectrum X[f], f = 0..M.
    cf2* out = spec + (size_t)sig * SPEC_STRIDE;
    #pragma unroll
    for (int m = 0; m < 16; ++m) {
        const int f = tid + 512*m;
        const int fb = (M_LEN - f) & (M_LEN - 1);
        cf2 Za = A[swz(pos(f))];
        cf2 Zb = A[swz(pos(fb))];
        cf2 E = (cf2){0.5f*(Za.x + Zb.x), 0.5f*(Za.y - Zb.y)};
        cf2 D = (cf2){Za.x - Zb.x, Za.y + Zb.y};
        cf2 O = (cf2){0.5f*D.y, -0.5f*D.x};
        float sn, cs;
        __sincosf(-PI_F * (float)f / 8192.f, &sn, &cs);
        cf2 val = E + (cf2){cs*O.x - sn*O.y, cs*O.y + sn*O.x};
        if (isW) {   // V(f) = conj(W(f)) * e^{-i pi k/8192}, k exact int mod
            const int k = (4094 * f) & (L_LEN - 1);
            float psn, pcs; __sincosf(-PI_F * (float)k / 8192.f, &psn, &pcs);
            val = cmul((cf2){val.x, -val.y}, (cf2){pcs, psn});
        }
        out[f] = val;
    }
    if (tid == 0) {   // f = 8192
        cf2 Za = A[swz(0)];
        cf2 val = (cf2){Za.x - Za.y, 0.f};
        if (isW) {   // k(8192) = 8192 -> phase = (-1, 0)
            val = (cf2){-val.x, 0.f};
        }
        out[M_LEN] = val;
    }
}

// ---------------------------------------------------------------------------
// Kernel 2: per (b,n,c): S[f] = X[f]*V[f]*conj(H[f]) (V = whitening+phase,
// precomputed by fwd's W blocks); Hermitian pack fused into the product pass;
// 3 radix-16 LDS stages; final radix-2 fused with max (R6 structure).
// ---------------------------------------------------------------------------
__global__ __launch_bounds__(NT, 4)
void inv_fft_kernel(const cf2* __restrict__ spec, const cf2* __restrict__ T,
                    const float* __restrict__ hh, float* __restrict__ zarr) {
    __shared__ __attribute__((aligned(16))) cf2 A[M_LEN];   // 64 KB
    const int idx0 = blockIdx.x;
    const int c = idx0 & 1;
    const int n = (idx0 >> 1) % NTPL;
    const int b = idx0 / (2 * NTPL);
    const int tid = threadIdx.x;

    const cf2* Xs = spec + (size_t)(b*2 + c)      * SPEC_STRIDE;
    const cf2* Vs = spec + (size_t)(64 + c)       * SPEC_STRIDE;
    const cf2* Hs = spec + (size_t)(66 + n*2 + c) * SPEC_STRIDE;
    const float4* X4 = (const float4*)Xs;
    const float4* V4 = (const float4*)Vs;
    const float4* H4 = (const float4*)Hs;
    const float4* T4 = (const float4*)T;
    const int g0 = tid ^ ((tid >> 4) & 15);

    // Fused product + Hermitian pack: thread t handles f = 2t+1024m+{0,1}
    // (f in [0,4096)) and partners 8192-f. Writes all of Z'[0..8191].
    #pragma unroll
    for (int m = 0; m < 4; ++m) {
        const int u = 2*tid + 1024*m;
        float4 xf = X4[tid + 512*m], vf = V4[tid + 512*m], hf = H4[tid + 512*m];
        cf2 Sa0 = cmulc(cmul((cf2){xf.x, xf.y}, (cf2){vf.x, vf.y}), (cf2){hf.x, hf.y});
        cf2 Sa1 = cmulc(cmul((cf2){xf.z, xf.w}, (cf2){vf.z, vf.w}), (cf2){hf.z, hf.w});
        cf2 Sb0 = cmulc(cmul(Xs[M_LEN - u],     Vs[M_LEN - u]),     Hs[M_LEN - u]);
        cf2 Sb1 = cmulc(cmul(Xs[M_LEN - 1 - u], Vs[M_LEN - 1 - u]), Hs[M_LEN - 1 - u]);
        float4 tw = T4[tid + 512*m];          // T[u], T[u+1]
        // f = u
        float cs0 = tw.x, sn0 = -tw.y;
        float Ex0 = 0.5f*(Sa0.x + Sb0.x), Ey0 = 0.5f*(Sa0.y - Sb0.y);
        float Dx0 = Sa0.x - Sb0.x,        Dy0 = Sa0.y + Sb0.y;
        float Ox0 = 0.5f*(cs0*Dx0 - sn0*Dy0), Oy0 = 0.5f*(cs0*Dy0 + sn0*Dx0);
        // f = u+1
        float cs1 = tw.z, sn1 = -tw.w;
        float Ex1 = 0.5f*(Sa1.x + Sb1.x), Ey1 = 0.5f*(Sa1.y - Sb1.y);
        float Dx1 = Sa1.x - Sb1.x,        Dy1 = Sa1.y + Sb1.y;
        float Ox1 = 0.5f*(cs1*Dx1 - sn1*Dy1), Oy1 = 0.5f*(cs1*Dy1 + sn1*Dx1);
        ((float4*)A)[g0 + 512*m] = make_float4(Ex0 - Oy0, Ey0 + Ox0,
                                               Ex1 - Oy1, Ey1 + Ox1);
        if (u > 0) A[swz(M_LEN - u)] = (cf2){Ex0 + Oy0, Ox0 - Ey0};
        A[swz(M_LEN - 1 - u)] = (cf2){Ex1 + Oy1, Ox1 - Ey1};
    }
    if (tid == 0) {   // f = 4096 (self-paired)
        cf2 S = cmulc(cmul(Xs[4096], Vs[4096]), Hs[4096]);
        A[swz(4096)] = (cf2){S.x, -S.y};
    }
    __syncthreads();

    {   // stage 1: stride 512, es = 2*tid
        int idx[16]; const int b0 = swz(tid);
        #pragma unroll
        for (int nn = 0; nn < 16; ++nn) idx[nn] = b0 + 512*nn;
        butterfly16<+1>(A, idx, ldT<+1>(T, 2*tid));
    }
    __syncthreads();
    {   // stage 2: stride 32, es = 32*j
        const int blk = tid >> 5, j = tid & 31, jb = blk*512;
        int idx[16];
        #pragma unroll
        for (int nn = 0; nn < 16; ++nn) idx[nn] = jb + 32*nn + (j ^ (2*nn));
        butterfly16<+1>(A, idx, ldT<+1>(T, 32*j));
    }
    __syncthreads();
    {   // stage 3: stride 2, es = 512*j
        const int blk = tid >> 1, j = tid & 1;
        const int xv = (blk & 15) << 1, b3 = blk*32 + j;
        int idx[16];
        #pragma unroll
        for (int nn = 0; nn < 16; ++nn) idx[nn] = b3 + ((2*nn) ^ xv);
        cf2 w1 = j ? (cf2){C16, S16} : (cf2){1.f, 0.f};
        butterfly16<+1>(A, idx, w1);
    }
    __syncthreads();

    // Final radix-2 fused with max over re/im of every time sample (b128).
    float mx = -INFINITY;
    #pragma unroll
    for (int m = 0; m < 8; ++m) {
        float4 pq = ((const float4*)A)[g0 + 512*m];
        mx = fmaxf(mx, fmaxf(fmaxf(pq.x + pq.z, pq.y + pq.w),
                             fmaxf(pq.x - pq.z, pq.y - pq.w)));
    }
    __syncthreads();   // all reads of A done before reusing it as scratch
    for (int off = 32; off > 0; off >>= 1)
        mx = fmaxf(mx, __shfl_xor(mx, off));
    const int lane = tid & 63, wv = tid >> 6;   // 8 waves
    float* redf = (float*)A;
    if (lane == 0) redf[wv] = mx;
    __syncthreads();
    if (tid == 0) {
        float mm = redf[0];
        for (int i = 1; i < NT/64; ++i) mm = fmaxf(mm, redf[i]);
        zarr[(b*2 + c)*NTPL + n] = mm / ((float)M_LEN * hh[n*2 + c]);
    }
}

// ---------------------------------------------------------------------------
// Kernel 3: tiny CNN/MLP head. One block per batch element.
// ---------------------------------------------------------------------------
__global__ __launch_bounds__(256)
void head_kernel(const float* __restrict__ zarr,
                 const float* __restrict__ W1, const float* __restrict__ b1,
                 const float* __restrict__ W2, const float* __restrict__ b2,
                 const float* __restrict__ W3, const float* __restrict__ b3,
                 const float* __restrict__ W4, const float* __restrict__ b4,
                 float* __restrict__ out) {
    __shared__ float zl[2][NTPL];
    __shared__ float s1[16][48];
    __shared__ float p1[16][16];
    __shared__ float s2[32][14];
    __shared__ float hflat[128];
    __shared__ float h1[32];
    const int b = blockIdx.x, tid = threadIdx.x;

    for (int i = tid; i < 2*NTPL; i += 256) zl[i/NTPL][i%NTPL] = zarr[b*2*NTPL + i];
    __syncthreads();
    for (int i = tid; i < 16*48; i += 256) {
        const int o = i / 48, t = i % 48;
        float acc = b1[o];
        #pragma unroll
        for (int cc = 0; cc < 2; ++cc)
            #pragma unroll
            for (int k = 0; k < 3; ++k)
                acc += zl[cc][t+k] * W1[o*6 + cc*3 + k];
        s1[o][t] = 1.f / (1.f + __expf(-acc));
    }
    __syncthreads();
    for (int i = tid; i < 16*16; i += 256) {
        const int o = i / 16, u = i % 16;
        p1[o][u] = fmaxf(fmaxf(s1[o][3*u], s1[o][3*u+1]), s1[o][3*u+2]);
    }
    __syncthreads();
    for (int i = tid; i < 32*14; i += 256) {
        const int o = i / 14, t = i % 14;
        float acc = b2[o];
        for (int cc = 0; cc < 16; ++cc)
            #pragma unroll
            for (int k = 0; k < 3; ++k)
                acc += p1[cc][t+k] * W2[o*48 + cc*3 + k];
        s2[o][t] = 1.f / (1.f + __expf(-acc));
    }
    __syncthreads();
    for (int i = tid; i < 128; i += 256) {
        const int o = i / 4, u = i % 4;
        hflat[i] = fmaxf(fmaxf(s2[o][3*u], s2[o][3*u+1]), s2[o][3*u+2]);
    }
    __syncthreads();
    if (tid < 32) {
        float acc = b3[tid];
        for (int j = 0; j < 128; ++j) acc += hflat[j] * W3[tid*128 + j];
        h1[tid] = fmaxf(acc, 0.f);
    }
    __syncthreads();
    if (tid < 2) {
        float acc = b4[tid];
        for (int j = 0; j < 32; ++j) acc += h1[j] * W4[tid*32 + j];
        out[b*2 + tid] = acc;
    }
}

extern "C" void kernel_launch(void* const* d_in, const int* in_sizes, int n_in,
                              void* d_out, int out_size, void* d_ws, size_t ws_size,
                              hipStream_t stream) {
    const float* xi   = (const float*)d_in[0];
    const float* Sw   = (const float*)d_in[1];
    const float* tmpl = (const float*)d_in[2];
    const float* hh   = (const float*)d_in[3];
    const float* W1   = (const float*)d_in[4];
    const float* b1   = (const float*)d_in[5];
    const float* W2   = (const float*)d_in[6];
    const float* b2   = (const float*)d_in[7];
    const float* W3   = (const float*)d_in[8];
    const float* b3   = (const float*)d_in[9];
    const float* W4   = (const float*)d_in[10];
    const float* b4   = (const float*)d_in[11];
    float* out = (float*)d_out;

    cf2* T16  = (cf2*)d_ws;                         // 16384 cf2 = 128 KB
    cf2* spec = T16 + 16384;                        // NSIG * SPEC_STRIDE cf2
    float* zarr = (float*)(spec + (size_t)NSIG * SPEC_STRIDE);

    // fwd grid: NSIG FFT blocks + 32 twiddle-table writer blocks.
    // W blocks write V = conj(W)*phase, so no premul kernel is needed.
    fwd_fft_kernel<<<dim3(NSIG + 32), dim3(NT), 0, stream>>>(xi, Sw, tmpl, T16, spec);
    inv_fft_kernel<<<dim3(BB * NTPL * 2), dim3(NT), 0, stream>>>(spec, T16, hh, zarr);
    head_kernel<<<dim3(BB), dim3(256), 0, stream>>>(zarr, W1, b1, W2, b2, W3, b3, W4, b4, out);
}